// Round 2
// baseline (144.807 us; speedup 1.0000x reference)
//
#include <hip/hip_runtime.h>

// out[b,h] = sum_{i,j} cb[h, i*64+j] * in1[b,i] * in2[b,j]
// B = 4096, dim1 = dim2 = 64, H = 4096.
//
// Round-9 = round-7 inner loop (readlane broadcast, pair fusion, float2
// batch packing) DEQUARTERED: all 4 row-pair quarters per wave compute
// back-to-back into registers with no intervening barriers, then one
// syncthreads -> full 64h x 128b tile staged into LDS (aliased over the
// dead s1v input buffer) -> one syncthreads -> 256B/row coalesced flush.
// Barriers per block: 8 -> 2 (one vmcnt store-drain instead of 4); the
// 4 independent row-pair chains give the scheduler ILP to hide LDS latency.

typedef float vf2 __attribute__((ext_vector_type(2)));

#define SDIM 66   // s1v/s2v row stride in float2 units (16B-aligned rows)
#define SOHF 66   // so row stride in floats

__constant__ int   kStart[7] = {0, 64, 496, 1376, 2496, 3360, 3888};
__constant__ unsigned kMagic[7] = {262144u, 87382u, 52429u, 37450u, 29128u, 23832u, 20165u}; // 2^18/d rounded up, d=2*l3+1
__constant__ int   kVpOff[7] = {0, 4, 13, 24, 34, 40, 43};
__constant__ unsigned char kVp[44] = {
  0, 5, 10, 15,                                  // l3=0
  1, 4, 5, 6, 9, 10, 11, 14, 15,                 // l3=1
  2, 5, 6, 7, 8, 9, 10, 11, 13, 14, 15,          // l3=2 ((1,3) before (2,0))
  3, 6, 7, 9, 10, 11, 12, 13, 14, 15,            // l3=3 ((2,3) before (3,0))
  7, 10, 11, 13, 14, 15,                         // l3=4
  11, 14, 15,                                    // l3=5
  15};                                           // l3=6
__constant__ int kBase[4] = {0, 4, 16, 36};  // offset of first slot of each l

__device__ __forceinline__ void decode_h(int h, int& i1, int& i2,
                                         int& n1, int& n2, int& l1l2) {
  int l3 = (h >= 64) + (h >= 496) + (h >= 1376) + (h >= 2496) + (h >= 3360) + (h >= 3888);
  unsigned hl = (unsigned)(h - kStart[l3]);
  int pair = (int)((hl * kMagic[l3]) >> 18);   // hl / (2*l3+1), exact in range
  int slot = pair & 15;
  int vp   = pair >> 4;
  l1l2 = (int)kVp[kVpOff[l3] + vp];
  int l1 = l1l2 >> 2, l2 = l1l2 & 3;
  n1 = 2 * l1 + 1;
  n2 = 2 * l2 + 1;
  i1 = kBase[l1] + (slot >> 2) * n1;
  i2 = kBase[l2] + (slot & 3) * n2;
}

// ---- prep: compact cb rows + decode metadata (layout unchanged) ----
__global__ __launch_bounds__(256) void prep_kernel(const float* __restrict__ cb,
                                                   float* __restrict__ table,
                                                   int* __restrict__ meta) {
  int idx = blockIdx.x * 256 + threadIdx.x;   // 1024 blocks -> 262144 = 4096*64
  int h = idx >> 6, e = idx & 63;
  int i1, i2, n1, n2, c;
  decode_h(h, i1, i2, n1, n2, c);
  if (e == 0) meta[h] = i1 | (i2 << 8) | (c << 16);
  unsigned mg = (n2 == 1) ? 65536u : (n2 == 3) ? 21846u : (n2 == 5) ? 13108u : 9363u;
  int qi = (int)(((unsigned)e * mg) >> 16);   // e / n2, exact for e < 64
  int rj = e - qi * n2;
  float v = 0.f;
  if (e < n1 * n2) v = cb[(size_t)h * 4096 + (i1 + qi) * 64 + (i2 + rj)];
  table[(size_t)h * 64 + e] = v;
}

__device__ __forceinline__ float lane_bcast(float v, int l) {
  union { float f; int i; } u;
  u.f = v;
  u.i = __builtin_amdgcn_readlane(u.i, l);
  return u.f;
}

__device__ __forceinline__ vf2 splat(float c) { vf2 r; r.x = c; r.y = c; return r; }

// single row, 2 batches packed
template <int N1, int N2>
__device__ __forceinline__ vf2 inner_tp(float vrow,
                                        const vf2* __restrict__ s1r,
                                        const vf2* __restrict__ s2r,
                                        int i1, int i2) {
  vf2 bb[N2], aa[N1];
#pragma unroll
  for (int j = 0; j < N2; ++j) bb[j] = s2r[i2 + j];
#pragma unroll
  for (int i = 0; i < N1; ++i) aa[i] = s1r[i1 + i];
  vf2 acc0 = splat(0.f), acc1 = splat(0.f);
#pragma unroll
  for (int i = 0; i < N1; ++i) {
    vf2 t = splat(lane_bcast(vrow, i * N2)) * bb[0];
#pragma unroll
    for (int j = 1; j < N2; ++j)
      t = __builtin_elementwise_fma(splat(lane_bcast(vrow, i * N2 + j)), bb[j], t);
    if (i & 1) acc1 = __builtin_elementwise_fma(aa[i], t, acc1);
    else       acc0 = __builtin_elementwise_fma(aa[i], t, acc0);
  }
  return acc0 + acc1;
}

// fused same-run pair x 2 batches: aa/bb loaded once for both rows
template <int N1, int N2>
__device__ __forceinline__ void inner_tp2(float v0, float v1,
                                          const vf2* __restrict__ s1r,
                                          const vf2* __restrict__ s2r,
                                          int i1, int i2,
                                          vf2& o0, vf2& o1) {
  vf2 bb[N2], aa[N1];
#pragma unroll
  for (int j = 0; j < N2; ++j) bb[j] = s2r[i2 + j];
#pragma unroll
  for (int i = 0; i < N1; ++i) aa[i] = s1r[i1 + i];
  vf2 a0 = splat(0.f), a1 = splat(0.f), b0 = splat(0.f), b1 = splat(0.f);
#pragma unroll
  for (int i = 0; i < N1; ++i) {
    vf2 t0 = splat(lane_bcast(v0, i * N2)) * bb[0];
    vf2 t1 = splat(lane_bcast(v1, i * N2)) * bb[0];
#pragma unroll
    for (int j = 1; j < N2; ++j) {
      t0 = __builtin_elementwise_fma(splat(lane_bcast(v0, i * N2 + j)), bb[j], t0);
      t1 = __builtin_elementwise_fma(splat(lane_bcast(v1, i * N2 + j)), bb[j], t1);
    }
    if (i & 1) { a1 = __builtin_elementwise_fma(aa[i], t0, a1);
                 b1 = __builtin_elementwise_fma(aa[i], t1, b1); }
    else       { a0 = __builtin_elementwise_fma(aa[i], t0, a0);
                 b0 = __builtin_elementwise_fma(aa[i], t1, b0); }
  }
  o0 = a0 + a1;
  o1 = b0 + b1;
}

__global__ __launch_bounds__(512, 4) void tp_kernel(
    const float* __restrict__ in1, const float* __restrict__ in2,
    const float* __restrict__ table, const int* __restrict__ meta,
    float* __restrict__ out) {
  // s1v | s2v input staging; after compute, the so output tile (33792 B)
  // aliases s1v (inputs are dead past the first syncthreads).
  __shared__ __align__(16) char smem[64 * SDIM * 8 * 2];   // 67584 B -> 2 blocks/CU
  vf2* s1v = reinterpret_cast<vf2*>(smem);
  vf2* s2v = s1v + 64 * SDIM;
  float* so = reinterpret_cast<float*>(smem);   // 128 * SOHF floats, aliases s1v

  const int tid = threadIdx.x;
  const int b0 = blockIdx.x << 7;   // batch tile (128)
  const int h0 = blockIdx.y << 6;   // h tile (64)
  const int w = tid >> 6;           // wave id 0..7: rows 16q + 2w (+1), q=0..3
  const int t = tid & 63;           // lane = batch PAIR (2t, 2t+1)

  // ---- prefetch ALL 4 quarters' cb entries (lane t = entry t) + meta ----
  const float* tb = table + ((size_t)(h0 + 2 * w) << 6) + t;
  float cur[8];
#pragma unroll
  for (int q = 0; q < 4; ++q) {
    cur[2 * q]     = tb[q << 10];
    cur[2 * q + 1] = tb[(q << 10) + 64];
  }
  const int2* meta2 = reinterpret_cast<const int2*>(meta);
  int2 mq[4];
#pragma unroll
  for (int q = 0; q < 4; ++q)
    mq[q] = meta2[__builtin_amdgcn_readfirstlane((h0 >> 1) + 8 * q + w)];

  // ---- stage in1/in2 tiles, interleaving batch pairs into float2 ----
#pragma unroll
  for (int it = 0; it < 2; ++it) {
    int task = it * 512 + tid;         // 1024 tasks = 64 pairs x 16 float4
    int bp = task >> 4;                // batch pair 0..63
    int d4 = (task & 15) << 2;         // dim start
    const float* r0p = in1 + (size_t)(b0 + 2 * bp) * 64 + d4;
    const float* r1p = r0p + 64;
    float4 a0 = *reinterpret_cast<const float4*>(r0p);
    float4 a1 = *reinterpret_cast<const float4*>(r1p);
    vf2* p = &s1v[bp * SDIM + d4];
    vf2 u;
    u.x = a0.x; u.y = a1.x; p[0] = u;
    u.x = a0.y; u.y = a1.y; p[1] = u;
    u.x = a0.z; u.y = a1.z; p[2] = u;
    u.x = a0.w; u.y = a1.w; p[3] = u;
    const float* q0p = in2 + (size_t)(b0 + 2 * bp) * 64 + d4;
    const float* q1p = q0p + 64;
    float4 c0 = *reinterpret_cast<const float4*>(q0p);
    float4 c1 = *reinterpret_cast<const float4*>(q1p);
    vf2* p2 = &s2v[bp * SDIM + d4];
    u.x = c0.x; u.y = c1.x; p2[0] = u;
    u.x = c0.y; u.y = c1.y; p2[1] = u;
    u.x = c0.z; u.y = c1.z; p2[2] = u;
    u.x = c0.w; u.y = c1.w; p2[3] = u;
  }
  __syncthreads();

  const vf2* s1r = &s1v[t * SDIM];
  const vf2* s2r = &s2v[t * SDIM];

  // ---- compute all 4 row-pairs back-to-back, NO barriers between ----
  vf2 r[8];
#pragma unroll
  for (int q = 0; q < 4; ++q) {
    int mm0 = mq[q].x, mm1 = mq[q].y;
    float c0 = cur[2 * q], c1 = cur[2 * q + 1];
    vf2 r0 = splat(0.f), r1 = splat(0.f);
    if (mm0 == mm1) {
      int i1 = mm0 & 255, i2 = (mm0 >> 8) & 255;
#define TP2_CASE(L1, L2) \
      case (L1 * 4 + L2): inner_tp2<2 * L1 + 1, 2 * L2 + 1>(c0, c1, s1r, s2r, i1, i2, r0, r1); break;
      switch (mm0 >> 16) {
        TP2_CASE(0, 0) TP2_CASE(0, 1) TP2_CASE(0, 2) TP2_CASE(0, 3)
        TP2_CASE(1, 0) TP2_CASE(1, 1) TP2_CASE(1, 2) TP2_CASE(1, 3)
        TP2_CASE(2, 0) TP2_CASE(2, 1) TP2_CASE(2, 2) TP2_CASE(2, 3)
        TP2_CASE(3, 0) TP2_CASE(3, 1) TP2_CASE(3, 2) TP2_CASE(3, 3)
        default: break;
      }
#undef TP2_CASE
    } else {
#define TP_CASE(L1, L2, VR, DST, MI1, MI2) \
      case (L1 * 4 + L2): DST = inner_tp<2 * L1 + 1, 2 * L2 + 1>(VR, s1r, s2r, MI1, MI2); break;
      {
        int i1 = mm0 & 255, i2 = (mm0 >> 8) & 255;
        switch (mm0 >> 16) {
          TP_CASE(0, 0, c0, r0, i1, i2) TP_CASE(0, 1, c0, r0, i1, i2)
          TP_CASE(0, 2, c0, r0, i1, i2) TP_CASE(0, 3, c0, r0, i1, i2)
          TP_CASE(1, 0, c0, r0, i1, i2) TP_CASE(1, 1, c0, r0, i1, i2)
          TP_CASE(1, 2, c0, r0, i1, i2) TP_CASE(1, 3, c0, r0, i1, i2)
          TP_CASE(2, 0, c0, r0, i1, i2) TP_CASE(2, 1, c0, r0, i1, i2)
          TP_CASE(2, 2, c0, r0, i1, i2) TP_CASE(2, 3, c0, r0, i1, i2)
          TP_CASE(3, 0, c0, r0, i1, i2) TP_CASE(3, 1, c0, r0, i1, i2)
          TP_CASE(3, 2, c0, r0, i1, i2) TP_CASE(3, 3, c0, r0, i1, i2)
          default: break;
        }
      }
      {
        int i1 = mm1 & 255, i2 = (mm1 >> 8) & 255;
        switch (mm1 >> 16) {
          TP_CASE(0, 0, c1, r1, i1, i2) TP_CASE(0, 1, c1, r1, i1, i2)
          TP_CASE(0, 2, c1, r1, i1, i2) TP_CASE(0, 3, c1, r1, i1, i2)
          TP_CASE(1, 0, c1, r1, i1, i2) TP_CASE(1, 1, c1, r1, i1, i2)
          TP_CASE(1, 2, c1, r1, i1, i2) TP_CASE(1, 3, c1, r1, i1, i2)
          TP_CASE(2, 0, c1, r1, i1, i2) TP_CASE(2, 1, c1, r1, i1, i2)
          TP_CASE(2, 2, c1, r1, i1, i2) TP_CASE(2, 3, c1, r1, i1, i2)
          TP_CASE(3, 0, c1, r1, i1, i2) TP_CASE(3, 1, c1, r1, i1, i2)
          TP_CASE(3, 2, c1, r1, i1, i2) TP_CASE(3, 3, c1, r1, i1, i2)
          default: break;
        }
      }
#undef TP_CASE
    }
    r[2 * q] = r0;
    r[2 * q + 1] = r1;
  }

  __syncthreads();   // all s1v/s2v reads done -> safe to overwrite with so

  // ---- stage full 64h x 128b tile: so[batch][h], lane t owns b = 2t, 2t+1 ----
  {
    float* sa = &so[(2 * t) * SOHF + 2 * w];
    float* sb = &so[(2 * t + 1) * SOHF + 2 * w];
#pragma unroll
    for (int q = 0; q < 4; ++q) {
      vf2 va; va.x = r[2 * q].x; va.y = r[2 * q + 1].x;
      vf2 vb; vb.x = r[2 * q].y; vb.y = r[2 * q + 1].y;
      *reinterpret_cast<vf2*>(sa + 16 * q) = va;
      *reinterpret_cast<vf2*>(sb + 16 * q) = vb;
    }
  }
  __syncthreads();

  // ---- flush: thread -> (batch b = tid>>2, h chunk (tid&3)*16); 256B/row ----
  {
    int b = tid >> 2;
    int hs = (tid & 3) << 4;
    const float* sp = &so[b * SOHF + hs];
    float* op = out + (size_t)(b0 + b) * 4096 + h0 + hs;
#pragma unroll
    for (int k = 0; k < 4; ++k) {
      vf2 u0 = *reinterpret_cast<const vf2*>(sp + 4 * k);
      vf2 u1 = *reinterpret_cast<const vf2*>(sp + 4 * k + 2);
      float4 v; v.x = u0.x; v.y = u0.y; v.z = u1.x; v.w = u1.y;
      *reinterpret_cast<float4*>(op + 4 * k) = v;
    }
  }
}

extern "C" void kernel_launch(void* const* d_in, const int* in_sizes, int n_in,
                              void* d_out, int out_size, void* d_ws, size_t ws_size,
                              hipStream_t stream) {
  const float* in1 = (const float*)d_in[0];
  const float* in2 = (const float*)d_in[1];
  const float* cb  = (const float*)d_in[2];
  float* out = (float*)d_out;
  float* table = (float*)d_ws;                       // 4096*64*4 = 1 MB
  int* meta = (int*)((char*)d_ws + (size_t)4096 * 64 * 4);   // +16 KB
  (void)in_sizes; (void)n_in; (void)out_size; (void)ws_size;
  prep_kernel<<<1024, 256, 0, stream>>>(cb, table, meta);
  tp_kernel<<<dim3(32, 64), 512, 0, stream>>>(in1, in2, table, meta, out);
}

// Round 4
// 141.912 us; speedup vs baseline: 1.0204x; 1.0204x over previous
//
#include <hip/hip_runtime.h>

// out[b,h] = sum_{i,j} cb[h, i*64+j] * in1[b,i] * in2[b,j]
// B = 4096, dim1 = dim2 = 64, H = 4096.
//
// Round-10 = round-7 quarter structure (readlane broadcast, pair fusion,
// float2 batch packing, per-quarter flush) with the LDS INPUT STAGING
// REPLACED by direct global loads from a pre-interleaved, pre-transposed
// copy of in1/in2 (inter_kernel -> workspace, layout [btile][d][pair]).
// in1/in2 are 2 MB = L2/L3-resident, so fragment loads are coalesced
// vf2 cache hits. LDS drops 75 KB -> 8.7 KB (output tile only), enabling
// 4+ blocks/CU (32 waves, was 16) to hide load latency. R8/R9 showed the
// kernel is neither issue- nor barrier-bound: it is occupancy/latency-bound.

typedef float vf2 __attribute__((ext_vector_type(2)));

#define SOH 17    // so row stride (h-minor, odd -> spreads banks)

__constant__ int   kStart[7] = {0, 64, 496, 1376, 2496, 3360, 3888};
__constant__ unsigned kMagic[7] = {262144u, 87382u, 52429u, 37450u, 29128u, 23832u, 20165u}; // 2^18/d rounded up, d=2*l3+1
__constant__ int   kVpOff[7] = {0, 4, 13, 24, 34, 40, 43};
__constant__ unsigned char kVp[44] = {
  0, 5, 10, 15,                                  // l3=0
  1, 4, 5, 6, 9, 10, 11, 14, 15,                 // l3=1
  2, 5, 6, 7, 8, 9, 10, 11, 13, 14, 15,          // l3=2 ((1,3) before (2,0))
  3, 6, 7, 9, 10, 11, 12, 13, 14, 15,            // l3=3 ((2,3) before (3,0))
  7, 10, 11, 13, 14, 15,                         // l3=4
  11, 14, 15,                                    // l3=5
  15};                                           // l3=6
__constant__ int kBase[4] = {0, 4, 16, 36};  // offset of first slot of each l

__device__ __forceinline__ void decode_h(int h, int& i1, int& i2,
                                         int& n1, int& n2, int& l1l2) {
  int l3 = (h >= 64) + (h >= 496) + (h >= 1376) + (h >= 2496) + (h >= 3360) + (h >= 3888);
  unsigned hl = (unsigned)(h - kStart[l3]);
  int pair = (int)((hl * kMagic[l3]) >> 18);   // hl / (2*l3+1), exact in range
  int slot = pair & 15;
  int vp   = pair >> 4;
  l1l2 = (int)kVp[kVpOff[l3] + vp];
  int l1 = l1l2 >> 2, l2 = l1l2 & 3;
  n1 = 2 * l1 + 1;
  n2 = 2 * l2 + 1;
  i1 = kBase[l1] + (slot >> 2) * n1;
  i2 = kBase[l2] + (slot & 3) * n2;
}

// ---- prep: compact cb rows + decode metadata (layout unchanged) ----
__global__ __launch_bounds__(256) void prep_kernel(const float* __restrict__ cb,
                                                   float* __restrict__ table,
                                                   int* __restrict__ meta) {
  int idx = blockIdx.x * 256 + threadIdx.x;   // 1024 blocks -> 262144 = 4096*64
  int h = idx >> 6, e = idx & 63;
  int i1, i2, n1, n2, c;
  decode_h(h, i1, i2, n1, n2, c);
  if (e == 0) meta[h] = i1 | (i2 << 8) | (c << 16);
  unsigned mg = (n2 == 1) ? 65536u : (n2 == 3) ? 21846u : (n2 == 5) ? 13108u : 9363u;
  int qi = (int)(((unsigned)e * mg) >> 16);   // e / n2, exact for e < 64
  int rj = e - qi * n2;
  float v = 0.f;
  if (e < n1 * n2) v = cb[(size_t)h * 4096 + (i1 + qi) * 64 + (i2 + rj)];
  table[(size_t)h * 64 + e] = v;
}

// ---- interleave/transpose in1,in2 -> inT[btile][d][pair] (vf2) ----
// inT[(bt*64 + d)*64 + t] = (inX[bt*128 + 2t][d], inX[bt*128 + 2t+1][d])
__global__ __launch_bounds__(256) void inter_kernel(const float* __restrict__ in1,
                                                    const float* __restrict__ in2,
                                                    vf2* __restrict__ t1,
                                                    vf2* __restrict__ t2) {
  int idx = blockIdx.x * 256 + threadIdx.x;   // 512 blocks -> 131072
  int t = idx & 63;
  int d = (idx >> 6) & 63;
  int bt = idx >> 12;
  size_t src = (size_t)(bt * 128 + 2 * t) * 64 + d;
  vf2 u; u.x = in1[src]; u.y = in1[src + 64];
  t1[idx] = u;
  vf2 v; v.x = in2[src]; v.y = in2[src + 64];
  t2[idx] = v;
}

__device__ __forceinline__ float lane_bcast(float v, int l) {
  union { float f; int i; } u;
  u.f = v;
  u.i = __builtin_amdgcn_readlane(u.i, l);
  return u.f;
}

__device__ __forceinline__ vf2 splat(float c) { vf2 r; r.x = c; r.y = c; return r; }

// single row, 2 batches packed; g1/g2 = lane's column base in inT tiles
template <int N1, int N2>
__device__ __forceinline__ vf2 inner_tp(float vrow,
                                        const vf2* __restrict__ g1,
                                        const vf2* __restrict__ g2,
                                        int i1, int i2) {
  const vf2* ap = g1 + (i1 << 6);
  const vf2* bp = g2 + (i2 << 6);
  vf2 bb[N2], aa[N1];
#pragma unroll
  for (int j = 0; j < N2; ++j) bb[j] = bp[j << 6];   // imm offsets j*512B
#pragma unroll
  for (int i = 0; i < N1; ++i) aa[i] = ap[i << 6];
  vf2 acc0 = splat(0.f), acc1 = splat(0.f);
#pragma unroll
  for (int i = 0; i < N1; ++i) {
    vf2 t = splat(lane_bcast(vrow, i * N2)) * bb[0];
#pragma unroll
    for (int j = 1; j < N2; ++j)
      t = __builtin_elementwise_fma(splat(lane_bcast(vrow, i * N2 + j)), bb[j], t);
    if (i & 1) acc1 = __builtin_elementwise_fma(aa[i], t, acc1);
    else       acc0 = __builtin_elementwise_fma(aa[i], t, acc0);
  }
  return acc0 + acc1;
}

// fused same-run pair x 2 batches: aa/bb loaded once for both rows
template <int N1, int N2>
__device__ __forceinline__ void inner_tp2(float v0, float v1,
                                          const vf2* __restrict__ g1,
                                          const vf2* __restrict__ g2,
                                          int i1, int i2,
                                          vf2& o0, vf2& o1) {
  const vf2* ap = g1 + (i1 << 6);
  const vf2* bp = g2 + (i2 << 6);
  vf2 bb[N2], aa[N1];
#pragma unroll
  for (int j = 0; j < N2; ++j) bb[j] = bp[j << 6];
#pragma unroll
  for (int i = 0; i < N1; ++i) aa[i] = ap[i << 6];
  vf2 a0 = splat(0.f), a1 = splat(0.f), b0 = splat(0.f), b1 = splat(0.f);
#pragma unroll
  for (int i = 0; i < N1; ++i) {
    vf2 t0 = splat(lane_bcast(v0, i * N2)) * bb[0];
    vf2 t1 = splat(lane_bcast(v1, i * N2)) * bb[0];
#pragma unroll
    for (int j = 1; j < N2; ++j) {
      t0 = __builtin_elementwise_fma(splat(lane_bcast(v0, i * N2 + j)), bb[j], t0);
      t1 = __builtin_elementwise_fma(splat(lane_bcast(v1, i * N2 + j)), bb[j], t1);
    }
    if (i & 1) { a1 = __builtin_elementwise_fma(aa[i], t0, a1);
                 b1 = __builtin_elementwise_fma(aa[i], t1, b1); }
    else       { a0 = __builtin_elementwise_fma(aa[i], t0, a0);
                 b0 = __builtin_elementwise_fma(aa[i], t1, b0); }
  }
  o0 = a0 + a1;
  o1 = b0 + b1;
}

__global__ __launch_bounds__(512, 8) void tp_kernel(
    const vf2* __restrict__ g1t, const vf2* __restrict__ g2t,
    const float* __restrict__ table, const int* __restrict__ meta,
    float* __restrict__ out) {
  __shared__ float so[128 * SOH];   // 8704 B -> LDS no longer caps occupancy

  const int tid = threadIdx.x;
  const int b0 = blockIdx.x << 7;   // batch tile (128)
  const int h0 = blockIdx.y << 6;   // h tile (64)
  const int w = tid >> 6;           // wave id 0..7: rows 16q+2w, +1
  const int t = tid & 63;           // lane = batch PAIR (2t, 2t+1)

  // wave's cb-table rows; lane t holds entry t. Prefetch quarter 0 now.
  const float* tb = table + ((size_t)(h0 + 2 * w) << 6) + t;
  float cur0 = tb[0];
  float cur1 = tb[64];
  const int2* meta2 = reinterpret_cast<const int2*>(meta);
  int2 mcur = meta2[__builtin_amdgcn_readfirstlane((h0 >> 1) + w)];

  // lane's column base in the interleaved-transposed input tiles
  const vf2* g1 = g1t + ((size_t)blockIdx.x << 12) + t;
  const vf2* g2 = g2t + ((size_t)blockIdx.x << 12) + t;

#pragma unroll 1
  for (int q = 0; q < 4; ++q) {
    // prefetch next quarter's cb pair + meta (clamped on last iteration)
    int qn = (q < 3) ? (q + 1) : 0;
    float nxt0 = tb[qn << 10];
    float nxt1 = tb[(qn << 10) + 64];
    int2 mnxt = meta2[__builtin_amdgcn_readfirstlane((h0 >> 1) + 8 * qn + w)];

    int mm0 = mcur.x, mm1 = mcur.y;
    vf2 r0 = splat(0.f), r1 = splat(0.f);
    if (mm0 == mm1) {
      int i1 = mm0 & 255, i2 = (mm0 >> 8) & 255;
#define TP2_CASE(L1, L2) \
      case (L1 * 4 + L2): inner_tp2<2 * L1 + 1, 2 * L2 + 1>(cur0, cur1, g1, g2, i1, i2, r0, r1); break;
      switch (mm0 >> 16) {
        TP2_CASE(0, 0) TP2_CASE(0, 1) TP2_CASE(0, 2) TP2_CASE(0, 3)
        TP2_CASE(1, 0) TP2_CASE(1, 1) TP2_CASE(1, 2) TP2_CASE(1, 3)
        TP2_CASE(2, 0) TP2_CASE(2, 1) TP2_CASE(2, 2) TP2_CASE(2, 3)
        TP2_CASE(3, 0) TP2_CASE(3, 1) TP2_CASE(3, 2) TP2_CASE(3, 3)
        default: break;
      }
#undef TP2_CASE
    } else {
#define TP_CASE(L1, L2, VR, DST, MI1, MI2) \
      case (L1 * 4 + L2): DST = inner_tp<2 * L1 + 1, 2 * L2 + 1>(VR, g1, g2, MI1, MI2); break;
      {
        int i1 = mm0 & 255, i2 = (mm0 >> 8) & 255;
        switch (mm0 >> 16) {
          TP_CASE(0, 0, cur0, r0, i1, i2) TP_CASE(0, 1, cur0, r0, i1, i2)
          TP_CASE(0, 2, cur0, r0, i1, i2) TP_CASE(0, 3, cur0, r0, i1, i2)
          TP_CASE(1, 0, cur0, r0, i1, i2) TP_CASE(1, 1, cur0, r0, i1, i2)
          TP_CASE(1, 2, cur0, r0, i1, i2) TP_CASE(1, 3, cur0, r0, i1, i2)
          TP_CASE(2, 0, cur0, r0, i1, i2) TP_CASE(2, 1, cur0, r0, i1, i2)
          TP_CASE(2, 2, cur0, r0, i1, i2) TP_CASE(2, 3, cur0, r0, i1, i2)
          TP_CASE(3, 0, cur0, r0, i1, i2) TP_CASE(3, 1, cur0, r0, i1, i2)
          TP_CASE(3, 2, cur0, r0, i1, i2) TP_CASE(3, 3, cur0, r0, i1, i2)
          default: break;
        }
      }
      {
        int i1 = mm1 & 255, i2 = (mm1 >> 8) & 255;
        switch (mm1 >> 16) {
          TP_CASE(0, 0, cur1, r1, i1, i2) TP_CASE(0, 1, cur1, r1, i1, i2)
          TP_CASE(0, 2, cur1, r1, i1, i2) TP_CASE(0, 3, cur1, r1, i1, i2)
          TP_CASE(1, 0, cur1, r1, i1, i2) TP_CASE(1, 1, cur1, r1, i1, i2)
          TP_CASE(1, 2, cur1, r1, i1, i2) TP_CASE(1, 3, cur1, r1, i1, i2)
          TP_CASE(2, 0, cur1, r1, i1, i2) TP_CASE(2, 1, cur1, r1, i1, i2)
          TP_CASE(2, 2, cur1, r1, i1, i2) TP_CASE(2, 3, cur1, r1, i1, i2)
          TP_CASE(3, 0, cur1, r1, i1, i2) TP_CASE(3, 1, cur1, r1, i1, i2)
          TP_CASE(3, 2, cur1, r1, i1, i2) TP_CASE(3, 3, cur1, r1, i1, i2)
          default: break;
        }
      }
#undef TP_CASE
    }
    // so[batch][local_h]: r0 = row h_a {b2t, b2t+1}, r1 = row h_b
    {
      float* sa = &so[(2 * t) * SOH + 2 * w];
      sa[0] = r0.x; sa[1] = r1.x;
      float* sb = &so[(2 * t + 1) * SOH + 2 * w];
      sb[0] = r0.y; sb[1] = r1.y;
    }
    __syncthreads();

    // ---- flush quarter: 16 h x 128 b; 512 threads x float4 ----
    {
      int b = tid >> 2;                // batch row 0..127
      int hs = (tid & 3) << 2;         // h offset 0,4,8,12
      const float* sp = &so[b * SOH + hs];
      float4 v;
      v.x = sp[0]; v.y = sp[1]; v.z = sp[2]; v.w = sp[3];
      *reinterpret_cast<float4*>(out + (size_t)(b0 + b) * 4096 + h0 + 16 * q + hs) = v;
    }
    if (q < 3) __syncthreads();   // so reused next quarter
    cur0 = nxt0; cur1 = nxt1;
    mcur = mnxt;
  }
}

extern "C" void kernel_launch(void* const* d_in, const int* in_sizes, int n_in,
                              void* d_out, int out_size, void* d_ws, size_t ws_size,
                              hipStream_t stream) {
  const float* in1 = (const float*)d_in[0];
  const float* in2 = (const float*)d_in[1];
  const float* cb  = (const float*)d_in[2];
  float* out = (float*)d_out;
  char* ws = (char*)d_ws;
  float* table = (float*)ws;                               // 1 MB @ 0
  int*   meta  = (int*)(ws + ((size_t)1 << 20));           // 16 KB @ 1 MB
  vf2*   inT1  = (vf2*)(ws + ((size_t)2 << 20));           // 1 MB @ 2 MB
  vf2*   inT2  = (vf2*)(ws + ((size_t)3 << 20));           // 1 MB @ 3 MB
  (void)in_sizes; (void)n_in; (void)out_size; (void)ws_size;
  prep_kernel<<<1024, 256, 0, stream>>>(cb, table, meta);
  inter_kernel<<<512, 256, 0, stream>>>(in1, in2, inT1, inT2);
  tp_kernel<<<dim3(32, 64), 512, 0, stream>>>(inT1, inT2, table, meta, out);
}

// Round 5
// 140.267 us; speedup vs baseline: 1.0324x; 1.0117x over previous
//
#include <hip/hip_runtime.h>

// out[b,h] = sum_{i,j} cb[h, i*64+j] * in1[b,i] * in2[b,j]
// B = 4096, dim1 = dim2 = 64, H = 4096.
//
// Round-11: WRITE-PATH round. R7-R10 all pinned tp at ~41us regardless of
// inner-loop width, barriers, occupancy -> the invariant is the out-write
// pattern (256B segments @16KB stride, batch-major grid => co-resident
// blocks write disjoint row sets = scattered DRAM traffic, 1.9 TB/s).
// Changes: (1) grid swapped to h-fast so co-resident blocks cover the
// SAME 128 rows across consecutive h tiles (dense row coverage at DRAM);
// (2) all 4 quarters accumulate into one 128x64 LDS tile, flushed once
// with 256B-contiguous-per-row stores (full sectors, no amplification);
// (3) prep+inter merged into one kernel, inter reads coalesced (d-fast).

typedef float vf2 __attribute__((ext_vector_type(2)));

#define SOHF 66   // so row stride in floats (8B-aligned rows, spreads banks)

__constant__ int   kStart[7] = {0, 64, 496, 1376, 2496, 3360, 3888};
__constant__ unsigned kMagic[7] = {262144u, 87382u, 52429u, 37450u, 29128u, 23832u, 20165u}; // 2^18/d rounded up, d=2*l3+1
__constant__ int   kVpOff[7] = {0, 4, 13, 24, 34, 40, 43};
__constant__ unsigned char kVp[44] = {
  0, 5, 10, 15,                                  // l3=0
  1, 4, 5, 6, 9, 10, 11, 14, 15,                 // l3=1
  2, 5, 6, 7, 8, 9, 10, 11, 13, 14, 15,          // l3=2 ((1,3) before (2,0))
  3, 6, 7, 9, 10, 11, 12, 13, 14, 15,            // l3=3 ((2,3) before (3,0))
  7, 10, 11, 13, 14, 15,                         // l3=4
  11, 14, 15,                                    // l3=5
  15};                                           // l3=6
__constant__ int kBase[4] = {0, 4, 16, 36};  // offset of first slot of each l

__device__ __forceinline__ void decode_h(int h, int& i1, int& i2,
                                         int& n1, int& n2, int& l1l2) {
  int l3 = (h >= 64) + (h >= 496) + (h >= 1376) + (h >= 2496) + (h >= 3360) + (h >= 3888);
  unsigned hl = (unsigned)(h - kStart[l3]);
  int pair = (int)((hl * kMagic[l3]) >> 18);   // hl / (2*l3+1), exact in range
  int slot = pair & 15;
  int vp   = pair >> 4;
  l1l2 = (int)kVp[kVpOff[l3] + vp];
  int l1 = l1l2 >> 2, l2 = l1l2 & 3;
  n1 = 2 * l1 + 1;
  n2 = 2 * l2 + 1;
  i1 = kBase[l1] + (slot >> 2) * n1;
  i2 = kBase[l2] + (slot & 3) * n2;
}

// ---- merged prep (blocks 0..1023) + input interleave (blocks 1024..1535) ----
// prep: compact cb rows -> table[h][e] + meta[h]   (layout unchanged)
// inter: inT[(bt*64+d)*64 + t] = (inX[bt*128+2t][d], inX[bt*128+2t+1][d])
__global__ __launch_bounds__(256) void prep_inter_kernel(
    const float* __restrict__ cb, const float* __restrict__ in1,
    const float* __restrict__ in2, float* __restrict__ table,
    int* __restrict__ meta, vf2* __restrict__ t1, vf2* __restrict__ t2) {
  int bid = blockIdx.x;
  if (bid < 1024) {
    int idx = bid * 256 + threadIdx.x;   // 262144 = 4096*64
    int h = idx >> 6, e = idx & 63;
    int i1, i2, n1, n2, c;
    decode_h(h, i1, i2, n1, n2, c);
    if (e == 0) meta[h] = i1 | (i2 << 8) | (c << 16);
    unsigned mg = (n2 == 1) ? 65536u : (n2 == 3) ? 21846u : (n2 == 5) ? 13108u : 9363u;
    int qi = (int)(((unsigned)e * mg) >> 16);   // e / n2, exact for e < 64
    int rj = e - qi * n2;
    float v = 0.f;
    if (e < n1 * n2) v = cb[(size_t)h * 4096 + (i1 + qi) * 64 + (i2 + rj)];
    table[(size_t)h * 64 + e] = v;
  } else {
    int idx = (bid - 1024) * 256 + threadIdx.x;   // 131072
    int d = idx & 63;            // FAST -> coalesced 256B row reads
    int t = (idx >> 6) & 63;
    int bt = idx >> 12;
    size_t src = (size_t)(bt * 128 + 2 * t) * 64 + d;
    size_t dst = (size_t)((bt * 64 + d) * 64 + t);
    vf2 u; u.x = in1[src]; u.y = in1[src + 64];
    t1[dst] = u;
    vf2 v; v.x = in2[src]; v.y = in2[src + 64];
    t2[dst] = v;
  }
}

__device__ __forceinline__ float lane_bcast(float v, int l) {
  union { float f; int i; } u;
  u.f = v;
  u.i = __builtin_amdgcn_readlane(u.i, l);
  return u.f;
}

__device__ __forceinline__ vf2 splat(float c) { vf2 r; r.x = c; r.y = c; return r; }

// single row, 2 batches packed; g1/g2 = lane's column base in inT tiles
template <int N1, int N2>
__device__ __forceinline__ vf2 inner_tp(float vrow,
                                        const vf2* __restrict__ g1,
                                        const vf2* __restrict__ g2,
                                        int i1, int i2) {
  const vf2* ap = g1 + (i1 << 6);
  const vf2* bp = g2 + (i2 << 6);
  vf2 bb[N2], aa[N1];
#pragma unroll
  for (int j = 0; j < N2; ++j) bb[j] = bp[j << 6];   // imm offsets j*512B
#pragma unroll
  for (int i = 0; i < N1; ++i) aa[i] = ap[i << 6];
  vf2 acc0 = splat(0.f), acc1 = splat(0.f);
#pragma unroll
  for (int i = 0; i < N1; ++i) {
    vf2 t = splat(lane_bcast(vrow, i * N2)) * bb[0];
#pragma unroll
    for (int j = 1; j < N2; ++j)
      t = __builtin_elementwise_fma(splat(lane_bcast(vrow, i * N2 + j)), bb[j], t);
    if (i & 1) acc1 = __builtin_elementwise_fma(aa[i], t, acc1);
    else       acc0 = __builtin_elementwise_fma(aa[i], t, acc0);
  }
  return acc0 + acc1;
}

// fused same-run pair x 2 batches: aa/bb loaded once for both rows
template <int N1, int N2>
__device__ __forceinline__ void inner_tp2(float v0, float v1,
                                          const vf2* __restrict__ g1,
                                          const vf2* __restrict__ g2,
                                          int i1, int i2,
                                          vf2& o0, vf2& o1) {
  const vf2* ap = g1 + (i1 << 6);
  const vf2* bp = g2 + (i2 << 6);
  vf2 bb[N2], aa[N1];
#pragma unroll
  for (int j = 0; j < N2; ++j) bb[j] = bp[j << 6];
#pragma unroll
  for (int i = 0; i < N1; ++i) aa[i] = ap[i << 6];
  vf2 a0 = splat(0.f), a1 = splat(0.f), b0 = splat(0.f), b1 = splat(0.f);
#pragma unroll
  for (int i = 0; i < N1; ++i) {
    vf2 t0 = splat(lane_bcast(v0, i * N2)) * bb[0];
    vf2 t1 = splat(lane_bcast(v1, i * N2)) * bb[0];
#pragma unroll
    for (int j = 1; j < N2; ++j) {
      t0 = __builtin_elementwise_fma(splat(lane_bcast(v0, i * N2 + j)), bb[j], t0);
      t1 = __builtin_elementwise_fma(splat(lane_bcast(v1, i * N2 + j)), bb[j], t1);
    }
    if (i & 1) { a1 = __builtin_elementwise_fma(aa[i], t0, a1);
                 b1 = __builtin_elementwise_fma(aa[i], t1, b1); }
    else       { a0 = __builtin_elementwise_fma(aa[i], t0, a0);
                 b0 = __builtin_elementwise_fma(aa[i], t1, b0); }
  }
  o0 = a0 + a1;
  o1 = b0 + b1;
}

__global__ __launch_bounds__(512, 8) void tp_kernel(
    const vf2* __restrict__ g1t, const vf2* __restrict__ g2t,
    const float* __restrict__ table, const int* __restrict__ meta,
    float* __restrict__ out) {
  __shared__ float so[128 * SOHF];   // 33792 B full 128b x 64h tile -> 4 blk/CU

  const int tid = threadIdx.x;
  const int h0 = blockIdx.x << 6;   // h tile (64) -- FAST grid dim
  const int b0 = blockIdx.y << 7;   // batch tile (128)
  const int w = tid >> 6;           // wave id 0..7: rows 16q+2w, +1
  const int t = tid & 63;           // lane = batch PAIR (2t, 2t+1)

  // wave's cb-table rows; lane t holds entry t. Prefetch quarter 0 now.
  const float* tb = table + ((size_t)(h0 + 2 * w) << 6) + t;
  float cur0 = tb[0];
  float cur1 = tb[64];
  const int2* meta2 = reinterpret_cast<const int2*>(meta);
  int2 mcur = meta2[__builtin_amdgcn_readfirstlane((h0 >> 1) + w)];

  // lane's column base in the interleaved-transposed input tiles
  const vf2* g1 = g1t + ((size_t)blockIdx.y << 12) + t;
  const vf2* g2 = g2t + ((size_t)blockIdx.y << 12) + t;

#pragma unroll 1
  for (int q = 0; q < 4; ++q) {
    // prefetch next quarter's cb pair + meta (clamped on last iteration)
    int qn = (q < 3) ? (q + 1) : 0;
    float nxt0 = tb[qn << 10];
    float nxt1 = tb[(qn << 10) + 64];
    int2 mnxt = meta2[__builtin_amdgcn_readfirstlane((h0 >> 1) + 8 * qn + w)];

    int mm0 = mcur.x, mm1 = mcur.y;
    vf2 r0 = splat(0.f), r1 = splat(0.f);
    if (mm0 == mm1) {
      int i1 = mm0 & 255, i2 = (mm0 >> 8) & 255;
#define TP2_CASE(L1, L2) \
      case (L1 * 4 + L2): inner_tp2<2 * L1 + 1, 2 * L2 + 1>(cur0, cur1, g1, g2, i1, i2, r0, r1); break;
      switch (mm0 >> 16) {
        TP2_CASE(0, 0) TP2_CASE(0, 1) TP2_CASE(0, 2) TP2_CASE(0, 3)
        TP2_CASE(1, 0) TP2_CASE(1, 1) TP2_CASE(1, 2) TP2_CASE(1, 3)
        TP2_CASE(2, 0) TP2_CASE(2, 1) TP2_CASE(2, 2) TP2_CASE(2, 3)
        TP2_CASE(3, 0) TP2_CASE(3, 1) TP2_CASE(3, 2) TP2_CASE(3, 3)
        default: break;
      }
#undef TP2_CASE
    } else {
#define TP_CASE(L1, L2, VR, DST, MI1, MI2) \
      case (L1 * 4 + L2): DST = inner_tp<2 * L1 + 1, 2 * L2 + 1>(VR, g1, g2, MI1, MI2); break;
      {
        int i1 = mm0 & 255, i2 = (mm0 >> 8) & 255;
        switch (mm0 >> 16) {
          TP_CASE(0, 0, cur0, r0, i1, i2) TP_CASE(0, 1, cur0, r0, i1, i2)
          TP_CASE(0, 2, cur0, r0, i1, i2) TP_CASE(0, 3, cur0, r0, i1, i2)
          TP_CASE(1, 0, cur0, r0, i1, i2) TP_CASE(1, 1, cur0, r0, i1, i2)
          TP_CASE(1, 2, cur0, r0, i1, i2) TP_CASE(1, 3, cur0, r0, i1, i2)
          TP_CASE(2, 0, cur0, r0, i1, i2) TP_CASE(2, 1, cur0, r0, i1, i2)
          TP_CASE(2, 2, cur0, r0, i1, i2) TP_CASE(2, 3, cur0, r0, i1, i2)
          TP_CASE(3, 0, cur0, r0, i1, i2) TP_CASE(3, 1, cur0, r0, i1, i2)
          TP_CASE(3, 2, cur0, r0, i1, i2) TP_CASE(3, 3, cur0, r0, i1, i2)
          default: break;
        }
      }
      {
        int i1 = mm1 & 255, i2 = (mm1 >> 8) & 255;
        switch (mm1 >> 16) {
          TP_CASE(0, 0, cur1, r1, i1, i2) TP_CASE(0, 1, cur1, r1, i1, i2)
          TP_CASE(0, 2, cur1, r1, i1, i2) TP_CASE(0, 3, cur1, r1, i1, i2)
          TP_CASE(1, 0, cur1, r1, i1, i2) TP_CASE(1, 1, cur1, r1, i1, i2)
          TP_CASE(1, 2, cur1, r1, i1, i2) TP_CASE(1, 3, cur1, r1, i1, i2)
          TP_CASE(2, 0, cur1, r1, i1, i2) TP_CASE(2, 1, cur1, r1, i1, i2)
          TP_CASE(2, 2, cur1, r1, i1, i2) TP_CASE(2, 3, cur1, r1, i1, i2)
          TP_CASE(3, 0, cur1, r1, i1, i2) TP_CASE(3, 1, cur1, r1, i1, i2)
          TP_CASE(3, 2, cur1, r1, i1, i2) TP_CASE(3, 3, cur1, r1, i1, i2)
          default: break;
        }
      }
#undef TP_CASE
    }
    // accumulate into full tile: so[batch][h], cols 16q+2w, 16q+2w+1
    {
      vf2 va; va.x = r0.x; va.y = r1.x;   // batch 2t, rows h_a,h_b
      vf2 vb; vb.x = r0.y; vb.y = r1.y;   // batch 2t+1
      *reinterpret_cast<vf2*>(&so[(2 * t) * SOHF + 16 * q + 2 * w]) = va;
      *reinterpret_cast<vf2*>(&so[(2 * t + 1) * SOHF + 16 * q + 2 * w]) = vb;
    }
    cur0 = nxt0; cur1 = nxt1;
    mcur = mnxt;
  }

  __syncthreads();   // single barrier: tile complete

  // ---- flush: 4 insts x float4; lanes 0..15 cover 256B contiguous per row ----
#pragma unroll
  for (int k = 0; k < 4; ++k) {
    int row = 32 * k + (tid >> 4);    // 0..127
    int c4  = tid & 15;               // float4 index 0..15
    const float* sp = &so[row * SOHF + 4 * c4];
    vf2 u0 = *reinterpret_cast<const vf2*>(sp);
    vf2 u1 = *reinterpret_cast<const vf2*>(sp + 2);
    float4 v; v.x = u0.x; v.y = u0.y; v.z = u1.x; v.w = u1.y;
    *reinterpret_cast<float4*>(out + (size_t)(b0 + row) * 4096 + h0 + 4 * c4) = v;
  }
}

extern "C" void kernel_launch(void* const* d_in, const int* in_sizes, int n_in,
                              void* d_out, int out_size, void* d_ws, size_t ws_size,
                              hipStream_t stream) {
  const float* in1 = (const float*)d_in[0];
  const float* in2 = (const float*)d_in[1];
  const float* cb  = (const float*)d_in[2];
  float* out = (float*)d_out;
  char* ws = (char*)d_ws;
  float* table = (float*)ws;                               // 1 MB @ 0
  int*   meta  = (int*)(ws + ((size_t)1 << 20));           // 16 KB @ 1 MB
  vf2*   inT1  = (vf2*)(ws + ((size_t)2 << 20));           // 1 MB @ 2 MB
  vf2*   inT2  = (vf2*)(ws + ((size_t)3 << 20));           // 1 MB @ 3 MB
  (void)in_sizes; (void)n_in; (void)out_size; (void)ws_size;
  prep_inter_kernel<<<1536, 256, 0, stream>>>(cb, in1, in2, table, meta, inT1, inT2);
  tp_kernel<<<dim3(64, 32), 512, 0, stream>>>(inT1, inT2, table, meta, out);
}